// Round 3
// baseline (3246.245 us; speedup 1.0000x reference)
//
#include <hip/hip_runtime.h>
#include <math.h>

// Problem constants
constexpr int D = 768;
constexpr int H = 12;
constexpr int L = 6;
constexpr int B = 8;
constexpr int S = 256;
constexpr int DH = 64;      // D/H
constexpr int M = B * S;    // 2048 rows
constexpr int D4 = 4 * D;   // 3072

typedef _Float16 v2h __attribute__((ext_vector_type(2)));
typedef _Float16 v4h __attribute__((ext_vector_type(4)));
typedef _Float16 v8h __attribute__((ext_vector_type(8)));
typedef __fp16 f16x2 __attribute__((ext_vector_type(2)));
typedef float v4f __attribute__((ext_vector_type(4)));

// fp32 -> hi/lo fp16 split (Markidis). hi = rtz(x); lo = rtz(x - hi).
__device__ inline void cvt_split(float x, float y, v2h& hi, v2h& lo) {
    f16x2 h = __builtin_amdgcn_cvt_pkrtz(x, y);
    float rx = x - (float)h[0];
    float ry = y - (float)h[1];
    f16x2 l = __builtin_amdgcn_cvt_pkrtz(rx, ry);
    hi = __builtin_bit_cast(v2h, h);
    lo = __builtin_bit_cast(v2h, l);
}

__device__ inline void split1(float v, _Float16& hi, _Float16& lo) {
    f16x2 h = __builtin_amdgcn_cvt_pkrtz(v, v);
    float r = v - (float)h[0];
    f16x2 l = __builtin_amdgcn_cvt_pkrtz(r, r);
    hi = (_Float16)h[0];
    lo = (_Float16)l[0];
}

// ---------------------------------------------------------------------------
// Split-fp16 MFMA GEMM. A supplied as pre-split hi/lo half planes (lo plane
// at +asize halves). W fp32 (converted in-kernel). Output modes:
//   outp=0: fp32 C (atomic=1 -> atomicAdd, C pre-zeroed, bias part0 only)
//   outp=1: split planes P (hi) / P+csize (lo), no fp32 write.
// Per-block A = Aq if n0 < qsplit else Akv. W = n_per_mat-wide sub-matrices.
// Split-K via kpart = blockIdx.x / nblks, kchunk K-slice each.
// Block: 128x128 tile, 256 threads (4 waves, 2x2 of 64x64), BK=32.
// ---------------------------------------------------------------------------
__global__ __launch_bounds__(256) void gemm_mfma(
    const _Float16* __restrict__ Aq0, const _Float16* __restrict__ Akv0,
    const float* __restrict__ W0,  const float* __restrict__ bias0,
    float* __restrict__ C0, _Float16* __restrict__ P0,
    const _Float16* __restrict__ Aq1, const _Float16* __restrict__ Akv1,
    const float* __restrict__ W1,  const float* __restrict__ bias1,
    float* __restrict__ C1, _Float16* __restrict__ P1,
    int qsplit, int Kstride, int kchunk, int N, int n_per_mat, int nblks,
    int act, int atomic, int outp, long asize, long csize)
{
    const int z = blockIdx.z;
    const _Float16* __restrict__ Aq  = z ? Aq1  : Aq0;
    const _Float16* __restrict__ Akv = z ? Akv1 : Akv0;
    const float* __restrict__ Wb  = z ? W1   : W0;
    const float* __restrict__ biasz = z ? bias1 : bias0;
    float* __restrict__ C = z ? C1 : C0;
    _Float16* __restrict__ Ph_g = z ? P1 : P0;

    const int bx = blockIdx.x;
    const int nb = bx % nblks;
    const int kpart = bx / nblks;
    const int n0 = nb * 128;
    const int m0 = blockIdx.y * 128;
    const _Float16* __restrict__ Ah_g = ((n0 < qsplit) ? Aq : Akv) + (size_t)kpart * kchunk;
    const _Float16* __restrict__ Al_g = Ah_g + asize;
    const int sub = n0 / n_per_mat;
    const int nc0 = n0 - sub * n_per_mat;
    const float* __restrict__ W = Wb + (size_t)sub * Kstride * n_per_mat
                                     + (size_t)kpart * kchunk * n_per_mat;
    const float* __restrict__ bias = (kpart == 0) ? biasz : nullptr;

    const int tid = threadIdx.x;
    const int lane = tid & 63;
    const int wave = tid >> 6;
    const int wm = (wave & 1) * 64;
    const int wn = (wave >> 1) * 64;

    // LDS planes: [row][k], row stride 40 halves
    __shared__ _Float16 sm[4 * 128 * 40];
    _Float16* Ah = sm;
    _Float16* Al = sm + 128 * 40;
    _Float16* Bh = sm + 2 * 128 * 40;
    _Float16* Bl = sm + 3 * 128 * 40;

    v4f acc[4][4];
    #pragma unroll
    for (int i = 0; i < 4; ++i)
        #pragma unroll
        for (int j = 0; j < 4; ++j)
            acc[i][j] = (v4f){0.f, 0.f, 0.f, 0.f};

    const int ar = tid >> 2;            // A row 0..63 (+64i)
    const int ac = (tid & 3) * 8;       // A k-col (8 halves)
    const int bn = tid & 127;           // B col
    const int bk0 = (tid >> 7) * 16;    // B k-row base

    const int fm = lane & 15;
    const int fk = (lane >> 4) * 8;

    v8h avh[2], avl[2], avh2[2], avl2[2];
    float bv[16], bv2[16];
    // prologue load (k0 = 0)
    #pragma unroll
    for (int i = 0; i < 2; ++i) {
        avh[i] = *(const v8h*)(Ah_g + (size_t)(m0 + ar + 64 * i) * Kstride + ac);
        avl[i] = *(const v8h*)(Al_g + (size_t)(m0 + ar + 64 * i) * Kstride + ac);
    }
    #pragma unroll
    for (int j = 0; j < 16; ++j)
        bv[j] = W[(size_t)(bk0 + j) * n_per_mat + nc0 + bn];

    for (int k0 = 0; k0 < kchunk; k0 += 32) {
        __syncthreads();   // previous iteration's fragment reads done

        // ---- LDS write (A pre-split; B converted here) ----
        #pragma unroll
        for (int i = 0; i < 2; ++i) {
            *(v8h*)&Ah[(ar + 64 * i) * 40 + ac] = avh[i];
            *(v8h*)&Al[(ar + 64 * i) * 40 + ac] = avl[i];
        }
        {
            v8h bha, bhb, bla, blb;
            #pragma unroll
            for (int j = 0; j < 4; ++j) {
                v2h h, l;
                cvt_split(bv[2 * j], bv[2 * j + 1], h, l);
                bha[2 * j] = h[0]; bha[2 * j + 1] = h[1];
                bla[2 * j] = l[0]; bla[2 * j + 1] = l[1];
            }
            #pragma unroll
            for (int j = 0; j < 4; ++j) {
                v2h h, l;
                cvt_split(bv[8 + 2 * j], bv[8 + 2 * j + 1], h, l);
                bhb[2 * j] = h[0]; bhb[2 * j + 1] = h[1];
                blb[2 * j] = l[0]; blb[2 * j + 1] = l[1];
            }
            *(v8h*)&Bh[bn * 40 + bk0] = bha;
            *(v8h*)&Bh[bn * 40 + bk0 + 8] = bhb;
            *(v8h*)&Bl[bn * 40 + bk0] = bla;
            *(v8h*)&Bl[bn * 40 + bk0 + 8] = blb;
        }
        __syncthreads();

        // ---- issue next iteration's global loads AFTER the barrier so they
        //      overlap the fragment reads + MFMA ----
        if (k0 + 32 < kchunk) {
            #pragma unroll
            for (int i = 0; i < 2; ++i) {
                avh2[i] = *(const v8h*)(Ah_g + (size_t)(m0 + ar + 64 * i) * Kstride + k0 + 32 + ac);
                avl2[i] = *(const v8h*)(Al_g + (size_t)(m0 + ar + 64 * i) * Kstride + k0 + 32 + ac);
            }
            #pragma unroll
            for (int j = 0; j < 16; ++j)
                bv2[j] = W[(size_t)(k0 + 32 + bk0 + j) * n_per_mat + nc0 + bn];
        }

        // ---- fragments + MFMA ----
        v8h fah[4], fal[4], fbh[4], fbl[4];
        #pragma unroll
        for (int i = 0; i < 4; ++i) {
            fah[i] = *(v8h*)&Ah[(wm + i * 16 + fm) * 40 + fk];
            fal[i] = *(v8h*)&Al[(wm + i * 16 + fm) * 40 + fk];
        }
        #pragma unroll
        for (int j = 0; j < 4; ++j) {
            fbh[j] = *(v8h*)&Bh[(wn + j * 16 + fm) * 40 + fk];
            fbl[j] = *(v8h*)&Bl[(wn + j * 16 + fm) * 40 + fk];
        }
        #pragma unroll
        for (int i = 0; i < 4; ++i)
            #pragma unroll
            for (int j = 0; j < 4; ++j) {
                acc[i][j] = __builtin_amdgcn_mfma_f32_16x16x32_f16(fah[i], fbh[j], acc[i][j], 0, 0, 0);
                acc[i][j] = __builtin_amdgcn_mfma_f32_16x16x32_f16(fah[i], fbl[j], acc[i][j], 0, 0, 0);
                acc[i][j] = __builtin_amdgcn_mfma_f32_16x16x32_f16(fal[i], fbh[j], acc[i][j], 0, 0, 0);
            }

        #pragma unroll
        for (int i = 0; i < 2; ++i) { avh[i] = avh2[i]; avl[i] = avl2[i]; }
        #pragma unroll
        for (int j = 0; j < 16; ++j) bv[j] = bv2[j];
    }

    // ---- epilogue ----
    const int er = (lane >> 4) * 4;
    const int ec = lane & 15;
    #pragma unroll
    for (int j = 0; j < 4; ++j) {
        const int col = n0 + wn + j * 16 + ec;
        const float bs = bias ? bias[col] : 0.0f;
        #pragma unroll
        for (int i = 0; i < 4; ++i) {
            #pragma unroll
            for (int r = 0; r < 4; ++r) {
                const int row = m0 + wm + i * 16 + er + r;
                float v = acc[i][j][r] + bs;
                if (act == 1)
                    v = 0.5f * v * (1.0f + erff(v * 0.7071067811865476f));
                if (outp) {
                    _Float16 hi, lo;
                    split1(v, hi, lo);
                    Ph_g[(size_t)row * N + col] = hi;
                    Ph_g[(size_t)row * N + col + csize] = lo;
                } else if (atomic) {
                    atomicAdd(&C[(size_t)row * N + col], v);
                } else {
                    C[(size_t)row * N + col] = v;
                }
            }
        }
    }
}

// ---------------------------------------------------------------------------
// MFMA attention, dual-stream (blockIdx.z). qkv given as split planes
// (hi at qkvh, lo at qkvh + M*2304), layout [M, 2304] halves.
// Block = (b, head, 64-query tile); 4 waves x 16 queries; grid.x = B*H*4.
// ---------------------------------------------------------------------------
__global__ __launch_bounds__(256) void attn_kernel(
    const _Float16* __restrict__ qkvh0, const int* __restrict__ mask0, float* __restrict__ hout0,
    const _Float16* __restrict__ qkvh1, const int* __restrict__ mask1, float* __restrict__ hout1)
{
    const _Float16* __restrict__ qkvh = blockIdx.z ? qkvh1 : qkvh0;
    const int* __restrict__ mask = blockIdx.z ? mask1 : mask0;
    float* __restrict__ hout = blockIdx.z ? hout1 : hout0;
    const _Float16* __restrict__ qkvl = qkvh + (size_t)M * 2304;

    const int blk = blockIdx.x;
    const int qt = blk & 3;           // 4 query tiles of 64
    const int bh = blk >> 2;
    const int head = bh % H;
    const int b = bh / H;
    const int tid = threadIdx.x;
    const int wave = tid >> 6;
    const int lane = tid & 63;
    const int qloc = lane & 15;       // operand m/n index
    const int rg = lane >> 4;         // k-chunk / row-group

    // K tile [key][d] in pass 1; V^T tile [d][key] in pass 2 (union).
    __shared__ _Float16 KVh[64 * 72];
    __shared__ _Float16 KVl[64 * 72];
    // Per-wave P' tiles [q 0..15][key 0..63], row stride 72.
    __shared__ _Float16 Ph[4][16 * 72];
    __shared__ _Float16 Pl[4][16 * 72];
    __shared__ float mpen[256];

    // mask penalties (keys of the KV sequence)
    mpen[tid] = -10000.0f * (1.0f - (float)mask[b * S + tid]);

    // ---- Q fragments (B-operand): lane -> q = qloc, k(d) = ks*32+rg*8+j
    const int qrow = b * S + qt * 64 + wave * 16 + qloc;
    const size_t qoff = (size_t)qrow * 2304 + head * DH + rg * 8;
    v8h qh[2], ql[2];
    #pragma unroll
    for (int ks = 0; ks < 2; ++ks) {
        qh[ks] = *(const v8h*)(qkvh + qoff + ks * 32);
        ql[ks] = *(const v8h*)(qkvl + qoff + ks * 32);
    }

    v4f acc_s[16];
    #pragma unroll
    for (int i = 0; i < 16; ++i) acc_s[i] = (v4f){0.f, 0.f, 0.f, 0.f};

    // ---- pass 1: scores S^T (A = K tile, B = Q) ----
    const int skey = tid & 63;           // staging: key row
    const int sseg = (tid >> 6) * 16;    // staging: d segment
    #pragma unroll
    for (int t = 0; t < 4; ++t) {
        __syncthreads();
        {
            const size_t off = (size_t)(b * S + t * 64 + skey) * 2304 + 768 + head * DH + sseg;
            const v8h hA = ((const v8h*)(qkvh + off))[0];
            const v8h hB = ((const v8h*)(qkvh + off))[1];
            const v8h lA = ((const v8h*)(qkvl + off))[0];
            const v8h lB = ((const v8h*)(qkvl + off))[1];
            *(v8h*)&KVh[skey * 72 + sseg] = hA;
            *(v8h*)&KVh[skey * 72 + sseg + 8] = hB;
            *(v8h*)&KVl[skey * 72 + sseg] = lA;
            *(v8h*)&KVl[skey * 72 + sseg + 8] = lB;
        }
        __syncthreads();
        #pragma unroll
        for (int sub = 0; sub < 4; ++sub) {
            v8h kh[2], kl[2];
            #pragma unroll
            for (int ks = 0; ks < 2; ++ks) {
                kh[ks] = *(v8h*)&KVh[(sub * 16 + qloc) * 72 + ks * 32 + rg * 8];
                kl[ks] = *(v8h*)&KVl[(sub * 16 + qloc) * 72 + ks * 32 + rg * 8];
            }
            v4f acc = acc_s[t * 4 + sub];
            #pragma unroll
            for (int ks = 0; ks < 2; ++ks) {
                acc = __builtin_amdgcn_mfma_f32_16x16x32_f16(kh[ks], qh[ks], acc, 0, 0, 0);
                acc = __builtin_amdgcn_mfma_f32_16x16x32_f16(kh[ks], ql[ks], acc, 0, 0, 0);
                acc = __builtin_amdgcn_mfma_f32_16x16x32_f16(kl[ks], qh[ks], acc, 0, 0, 0);
            }
            acc_s[t * 4 + sub] = acc;
        }
    }

    // ---- softmax (q = qloc; keys = mt*16 + rg*4 + r across 4 rg groups) ----
    float mx = -3.0e38f;
    #pragma unroll
    for (int mt = 0; mt < 16; ++mt) {
        float4 mp = *(const float4*)&mpen[mt * 16 + rg * 4];
        v4f s = acc_s[mt];
        s[0] = s[0] * 0.125f + mp.x;
        s[1] = s[1] * 0.125f + mp.y;
        s[2] = s[2] * 0.125f + mp.z;
        s[3] = s[3] * 0.125f + mp.w;
        acc_s[mt] = s;
        mx = fmaxf(mx, fmaxf(fmaxf(s[0], s[1]), fmaxf(s[2], s[3])));
    }
    mx = fmaxf(mx, __shfl_xor(mx, 16, 64));
    mx = fmaxf(mx, __shfl_xor(mx, 32, 64));
    float sum = 0.f;
    #pragma unroll
    for (int mt = 0; mt < 16; ++mt) {
        v4f s = acc_s[mt];
        s[0] = __expf(s[0] - mx);
        s[1] = __expf(s[1] - mx);
        s[2] = __expf(s[2] - mx);
        s[3] = __expf(s[3] - mx);
        acc_s[mt] = s;
        sum += (s[0] + s[1]) + (s[2] + s[3]);
    }
    sum += __shfl_xor(sum, 16, 64);
    sum += __shfl_xor(sum, 32, 64);
    const float inv = 1.0f / sum;

    // ---- pass 2: O = P' @ V (A = P', B = V^T) ----
    v4f acc_o[4];
    #pragma unroll
    for (int j = 0; j < 4; ++j) acc_o[j] = (v4f){0.f, 0.f, 0.f, 0.f};

    const int vk4 = (tid & 15) * 4;   // staging: key group
    const int vd4 = (tid >> 4) * 4;   // staging: d group
    #pragma unroll
    for (int t = 0; t < 4; ++t) {
        __syncthreads();   // previous tile's LDS reads done
        // write this wave's P' tile: [q = qloc][key = sub*16 + rg*4 + r]
        #pragma unroll
        for (int sub = 0; sub < 4; ++sub) {
            v4f p = acc_s[t * 4 + sub];
            v2h h01, l01, h23, l23;
            cvt_split(p[0], p[1], h01, l01);
            cvt_split(p[2], p[3], h23, l23);
            *(v2h*)&Ph[wave][qloc * 72 + sub * 16 + rg * 4] = h01;
            *(v2h*)&Ph[wave][qloc * 72 + sub * 16 + rg * 4 + 2] = h23;
            *(v2h*)&Pl[wave][qloc * 72 + sub * 16 + rg * 4] = l01;
            *(v2h*)&Pl[wave][qloc * 72 + sub * 16 + rg * 4 + 2] = l23;
        }
        // stage V^T tile: read V[key][d] pre-split, write [d][key]
        {
            v4h rh[4], rl[4];
            #pragma unroll
            for (int i = 0; i < 4; ++i) {
                const size_t off = (size_t)(b * S + t * 64 + vk4 + i) * 2304 + 1536 + head * DH + vd4;
                const v4h hv = *(const v4h*)(qkvh + off);
                const v4h lv = *(const v4h*)(qkvl + off);
                rh[0][i] = hv[0]; rh[1][i] = hv[1]; rh[2][i] = hv[2]; rh[3][i] = hv[3];
                rl[0][i] = lv[0]; rl[1][i] = lv[1]; rl[2][i] = lv[2]; rl[3][i] = lv[3];
            }
            #pragma unroll
            for (int j = 0; j < 4; ++j) {
                *(v4h*)&KVh[(vd4 + j) * 72 + vk4] = rh[j];
                *(v4h*)&KVl[(vd4 + j) * 72 + vk4] = rl[j];
            }
        }
        __syncthreads();
        v8h pah[2], pal[2];
        #pragma unroll
        for (int ks = 0; ks < 2; ++ks) {
            pah[ks] = *(v8h*)&Ph[wave][qloc * 72 + ks * 32 + rg * 8];
            pal[ks] = *(v8h*)&Pl[wave][qloc * 72 + ks * 32 + rg * 8];
        }
        #pragma unroll
        for (int j = 0; j < 4; ++j) {
            v4f acc = acc_o[j];
            #pragma unroll
            for (int ks = 0; ks < 2; ++ks) {
                v8h vbh = *(v8h*)&KVh[(j * 16 + qloc) * 72 + ks * 32 + rg * 8];
                v8h vbl = *(v8h*)&KVl[(j * 16 + qloc) * 72 + ks * 32 + rg * 8];
                acc = __builtin_amdgcn_mfma_f32_16x16x32_f16(pah[ks], vbh, acc, 0, 0, 0);
                acc = __builtin_amdgcn_mfma_f32_16x16x32_f16(pah[ks], vbl, acc, 0, 0, 0);
                acc = __builtin_amdgcn_mfma_f32_16x16x32_f16(pal[ks], vbh, acc, 0, 0, 0);
            }
            acc_o[j] = acc;
        }
    }

    // ---- epilogue: normalize + store. C-layout: row q = rg*4 + r, col d = j*16 + qloc
    #pragma unroll
    for (int r = 0; r < 4; ++r) {
        const float invr = __shfl(inv, rg * 4 + r, 64);
        const size_t row = (size_t)(b * S + qt * 64 + wave * 16 + rg * 4 + r);
        #pragma unroll
        for (int j = 0; j < 4; ++j)
            hout[row * D + head * DH + j * 16 + qloc] = acc_o[j][r] * invr;
    }
}

// ---------------------------------------------------------------------------
// Residual + LayerNorm (in-place), dual-stream via blockIdx.y.
// Also emits split-fp16 planes of the output (hi at p, lo at p + M*D).
// ---------------------------------------------------------------------------
__global__ __launch_bounds__(256) void ln_res_kernel(
    float* __restrict__ x0, const float* __restrict__ h0,
    const float* __restrict__ g0, const float* __restrict__ bb0, _Float16* __restrict__ p0,
    float* __restrict__ x1, const float* __restrict__ h1,
    const float* __restrict__ g1, const float* __restrict__ bb1, _Float16* __restrict__ p1)
{
    float* __restrict__ x = blockIdx.y ? x1 : x0;
    const float* __restrict__ h = blockIdx.y ? h1 : h0;
    const float* __restrict__ g = blockIdx.y ? g1 : g0;
    const float* __restrict__ bb = blockIdx.y ? bb1 : bb0;
    _Float16* __restrict__ ph = blockIdx.y ? p1 : p0;
    _Float16* __restrict__ pl = ph + (size_t)M * D;

    const int row = blockIdx.x;
    const int tid = threadIdx.x;
    const int wave = tid >> 6;
    const int lane = tid & 63;
    __shared__ float red[4];

    float v[3];
    #pragma unroll
    for (int i = 0; i < 3; ++i) {
        int c = tid + 256 * i;
        v[i] = x[(size_t)row * D + c] + h[(size_t)row * D + c];
    }
    float s = v[0] + v[1] + v[2];
    #pragma unroll
    for (int o = 32; o > 0; o >>= 1) s += __shfl_xor(s, o, 64);
    if (lane == 0) red[wave] = s;
    __syncthreads();
    const float mean = (red[0] + red[1] + red[2] + red[3]) * (1.0f / 768.0f);

    float qs = 0.f;
    #pragma unroll
    for (int i = 0; i < 3; ++i) { float d = v[i] - mean; qs += d * d; }
    #pragma unroll
    for (int o = 32; o > 0; o >>= 1) qs += __shfl_xor(qs, o, 64);
    __syncthreads();
    if (lane == 0) red[wave] = qs;
    __syncthreads();
    const float var = (red[0] + red[1] + red[2] + red[3]) * (1.0f / 768.0f);
    const float rstd = rsqrtf(var + 1e-12f);

    #pragma unroll
    for (int i = 0; i < 3; ++i) {
        int c = tid + 256 * i;
        float o = (v[i] - mean) * rstd * g[c] + bb[c];
        x[(size_t)row * D + c] = o;
        _Float16 hi, lo;
        split1(o, hi, lo);
        ph[(size_t)row * D + c] = hi;
        pl[(size_t)row * D + c] = lo;
    }
}

// ---------------------------------------------------------------------------
// Elementwise fp32 -> split-fp16 planes (for initial x/y).
// ---------------------------------------------------------------------------
__global__ __launch_bounds__(256) void split_kernel(
    const float* __restrict__ in0, _Float16* __restrict__ p0,
    const float* __restrict__ in1, _Float16* __restrict__ p1, long n)
{
    const float* __restrict__ in = blockIdx.y ? in1 : in0;
    _Float16* __restrict__ ph = blockIdx.y ? p1 : p0;
    _Float16* __restrict__ pl = ph + n;
    const size_t idx = ((size_t)blockIdx.x * 256 + threadIdx.x) * 4;
    float4 v = *(const float4*)(in + idx);
    v2h h0, l0, h1, l1;
    cvt_split(v.x, v.y, h0, l0);
    cvt_split(v.z, v.w, h1, l1);
    v4h hh, ll;
    hh[0] = h0[0]; hh[1] = h0[1]; hh[2] = h1[0]; hh[3] = h1[1];
    ll[0] = l0[0]; ll[1] = l0[1]; ll[2] = l1[0]; ll[3] = l1[1];
    *(v4h*)(ph + idx) = hh;
    *(v4h*)(pl + idx) = ll;
}

// ---------------------------------------------------------------------------
// Host launcher
// ---------------------------------------------------------------------------
extern "C" void kernel_launch(void* const* d_in, const int* in_sizes, int n_in,
                              void* d_out, int out_size, void* d_ws, size_t ws_size,
                              hipStream_t stream)
{
    const float* x    = (const float*)d_in[0];
    const float* y    = (const float*)d_in[1];
    const int*   xm   = (const int*)d_in[2];
    const int*   ym   = (const int*)d_in[3];
    const float* ax_w = (const float*)d_in[4];
    const float* ax_b = (const float*)d_in[5];
    const float* cx_w = (const float*)d_in[6];
    const float* cx_b = (const float*)d_in[7];
    const float* fx_w1 = (const float*)d_in[8];
    const float* fx_b1 = (const float*)d_in[9];
    const float* fx_w2 = (const float*)d_in[10];
    const float* fx_b2 = (const float*)d_in[11];
    const float* ay_w = (const float*)d_in[12];
    const float* ay_b = (const float*)d_in[13];
    const float* cy_w = (const float*)d_in[14];
    const float* cy_b = (const float*)d_in[15];
    const float* fy_w1 = (const float*)d_in[16];
    const float* fy_b1 = (const float*)d_in[17];
    const float* fy_w2 = (const float*)d_in[18];
    const float* fy_b2 = (const float*)d_in[19];
    const float* lnx_g = (const float*)d_in[20];
    const float* lnx_b = (const float*)d_in[21];
    const float* lny_g = (const float*)d_in[22];
    const float* lny_b = (const float*)d_in[23];

    float* xc = (float*)d_out;
    float* yc = xc + (size_t)M * D;

    // Workspace:
    //   big: qkvx-planes[M*D4 fl] qkvy-planes[M*D4 fl] hbx[M*D] hby[M*D]
    //        xp-planes[M*D fl] yp-planes[M*D fl]
    //   (qkv/mid buffers hold split halves: hi plane + lo plane = same bytes
    //    as the old fp32 buffer)
    const size_t need = ((size_t)2 * M * D4 + (size_t)4 * M * D) * sizeof(float);
    const bool big = ws_size >= need;
    float* ws0 = (float*)d_ws;
    float* qkvx = ws0;
    float* qkvy = big ? ws0 + (size_t)M * D4 : ws0;
    float* hbx = big ? qkvy + (size_t)M * D4 : qkvx + (size_t)M * D4;
    float* hby = big ? hbx + (size_t)M * D : hbx;
    _Float16* xp = (_Float16*)(hby + (size_t)M * D);
    _Float16* yp = xp + (size_t)2 * M * D;

    _Float16* qpx = (_Float16*)qkvx;   // qkv / ffn-mid planes, stream x
    _Float16* qpy = (_Float16*)qkvy;   // stream y

    (void)hipMemcpyAsync(xc, x, (size_t)M * D * sizeof(float), hipMemcpyDeviceToDevice, stream);
    (void)hipMemcpyAsync(yc, y, (size_t)M * D * sizeof(float), hipMemcpyDeviceToDevice, stream);
    split_kernel<<<dim3(M * D / 1024, 2), dim3(256), 0, stream>>>(x, xp, y, yp, (long)M * D);

    const dim3 blk(256);
    constexpr int KSPLIT = 4;   // ffn2 split-K factor

    const long aD  = (long)M * D;    // activation plane size (halves)
    const long aD4 = (long)M * D4;   // mid plane size

    auto qkv_gemm = [&](const _Float16* aq0, const _Float16* akv0, const float* w0, const float* bi0, _Float16* p0,
                        const _Float16* aq1, const _Float16* akv1, const float* w1, const float* bi1, _Float16* p1,
                        int nz) {
        gemm_mfma<<<dim3(2304 / 128, M / 128, nz), blk, 0, stream>>>(
            aq0, akv0, w0, bi0, nullptr, p0, aq1, akv1, w1, bi1, nullptr, p1,
            768, D, D, 2304, 768, 2304 / 128, 0, 0, 1, aD, (long)M * 2304);
    };
    auto ffn1_gemm = [&](const _Float16* a0, const float* w0, const float* bi0, _Float16* p0,
                         const _Float16* a1, const float* w1, const float* bi1, _Float16* p1, int nz) {
        gemm_mfma<<<dim3(D4 / 128, M / 128, nz), blk, 0, stream>>>(
            a0, a0, w0, bi0, nullptr, p0, a1, a1, w1, bi1, nullptr, p1,
            0, D, D, D4, D4, D4 / 128, 1, 0, 1, aD, aD4);
    };
    // split-K ffn2: C pre-zeroed; parts atomically accumulate fp32.
    auto ffn2_gemm_split = [&](const _Float16* a0, const float* w0, const float* bi0, float* c0,
                               const _Float16* a1, const float* w1, const float* bi1, float* c1, int nz) {
        gemm_mfma<<<dim3((D / 128) * KSPLIT, M / 128, nz), blk, 0, stream>>>(
            a0, a0, w0, bi0, c0, nullptr, a1, a1, w1, bi1, c1, nullptr,
            0, D4, D4 / KSPLIT, D, D, D / 128, 0, 1, 0, aD4, 0);
    };
    auto ffn2_gemm_seq = [&](const _Float16* a0, const float* w0, const float* bi0, float* c0,
                             const _Float16* a1, const float* w1, const float* bi1, float* c1, int nz) {
        gemm_mfma<<<dim3(D / 128, M / 128, nz), blk, 0, stream>>>(
            a0, a0, w0, bi0, c0, nullptr, a1, a1, w1, bi1, c1, nullptr,
            0, D4, D4, D, D, D / 128, 0, 0, 0, aD4, 0);
    };
    auto attn = [&](const _Float16* q0, const int* m0_, float* h0,
                    const _Float16* q1, const int* m1_, float* h1, int nz) {
        attn_kernel<<<dim3(B * H * 4, 1, nz), blk, 0, stream>>>(q0, m0_, h0, q1, m1_, h1);
    };
    auto ln = [&](float* x0, const float* h0, const float* g0, const float* b0, _Float16* p0,
                  float* x1, const float* h1, const float* g1, const float* b1, _Float16* p1, int ny) {
        ln_res_kernel<<<dim3(M, ny), blk, 0, stream>>>(x0, h0, g0, b0, p0, x1, h1, g1, b1, p1);
    };

    for (int l = 0; l < L; ++l) {
        const size_t wo = (size_t)l * 3 * D * D;
        const size_t bo = (size_t)l * 3 * D;
        const size_t f1o = (size_t)l * D * D4;
        const size_t f1bo = (size_t)l * D4;
        const size_t f2o = (size_t)l * D4 * D;
        const size_t f2bo = (size_t)l * D;

        if (big) {
            // self-attention x & y merged
            qkv_gemm(xp, xp, ax_w + wo, ax_b + bo, qpx,
                     yp, yp, ay_w + wo, ay_b + bo, qpy, 2);
            attn(qpx, xm, hbx, qpy, ym, hby, 2);
            ln(xc, hbx, lnx_g, lnx_b, xp, yc, hby, lny_g, lny_b, yp, 2);
            // cross-x (q from x, kv from y, mask ym)
            qkv_gemm(xp, yp, cx_w + wo, cx_b + bo, qpx,
                     xp, yp, cx_w + wo, cx_b + bo, qpx, 1);
            attn(qpx, ym, hbx, qpx, ym, hbx, 1);
            ln(xc, hbx, lnx_g + D, lnx_b + D, xp, xc, hbx, lnx_g + D, lnx_b + D, xp, 1);
            // cross-y (q from y, kv from updated x, mask xm)
            qkv_gemm(yp, xp, cy_w + wo, cy_b + bo, qpy,
                     yp, xp, cy_w + wo, cy_b + bo, qpy, 1);
            attn(qpy, xm, hby, qpy, xm, hby, 1);
            ln(yc, hby, lny_g + D, lny_b + D, yp, yc, hby, lny_g + D, lny_b + D, yp, 1);
            // FFN merged; ffn2 via split-K atomics into zeroed hbx/hby
            ffn1_gemm(xp, fx_w1 + f1o, fx_b1 + f1bo, qpx,
                      yp, fy_w1 + f1o, fy_b1 + f1bo, qpy, 2);
            (void)hipMemsetAsync(hbx, 0, (size_t)2 * M * D * sizeof(float), stream);
            ffn2_gemm_split(qpx, fx_w2 + f2o, fx_b2 + f2bo, hbx,
                            qpy, fy_w2 + f2o, fy_b2 + f2bo, hby, 2);
            ln(xc, hbx, lnx_g + 2 * D, lnx_b + 2 * D, xp,
               yc, hby, lny_g + 2 * D, lny_b + 2 * D, yp, 2);
        } else {
            // sequential fallback (aliased qkv/hb buffers)
            qkv_gemm(xp, xp, ax_w + wo, ax_b + bo, qpx, xp, xp, ax_w + wo, ax_b + bo, qpx, 1);
            attn(qpx, xm, hbx, qpx, xm, hbx, 1);
            ln(xc, hbx, lnx_g, lnx_b, xp, xc, hbx, lnx_g, lnx_b, xp, 1);
            qkv_gemm(yp, yp, ay_w + wo, ay_b + bo, qpy, yp, yp, ay_w + wo, ay_b + bo, qpy, 1);
            attn(qpy, ym, hby, qpy, ym, hby, 1);
            ln(yc, hby, lny_g, lny_b, yp, yc, hby, lny_g, lny_b, yp, 1);
            qkv_gemm(xp, yp, cx_w + wo, cx_b + bo, qpx, xp, yp, cx_w + wo, cx_b + bo, qpx, 1);
            attn(qpx, ym, hbx, qpx, ym, hbx, 1);
            ln(xc, hbx, lnx_g + D, lnx_b + D, xp, xc, hbx, lnx_g + D, lnx_b + D, xp, 1);
            qkv_gemm(yp, xp, cy_w + wo, cy_b + bo, qpy, yp, xp, cy_w + wo, cy_b + bo, qpy, 1);
            attn(qpy, xm, hby, qpy, xm, hby, 1);
            ln(yc, hby, lny_g + D, lny_b + D, yp, yc, hby, lny_g + D, lny_b + D, yp, 1);
            ffn1_gemm(xp, fx_w1 + f1o, fx_b1 + f1bo, qpx, xp, fx_w1 + f1o, fx_b1 + f1bo, qpx, 1);
            ffn2_gemm_seq(qpx, fx_w2 + f2o, fx_b2 + f2bo, hbx, qpx, fx_w2 + f2o, fx_b2 + f2bo, hbx, 1);
            ln(xc, hbx, lnx_g + 2 * D, lnx_b + 2 * D, xp, xc, hbx, lnx_g + 2 * D, lnx_b + 2 * D, xp, 1);
            ffn1_gemm(yp, fy_w1 + f1o, fy_b1 + f1bo, qpy, yp, fy_w1 + f1o, fy_b1 + f1bo, qpy, 1);
            ffn2_gemm_seq(qpy, fy_w2 + f2o, fy_b2 + f2bo, hby, qpy, fy_w2 + f2o, fy_b2 + f2bo, hby, 1);
            ln(yc, hby, lny_g + 2 * D, lny_b + 2 * D, yp, yc, hby, lny_g + 2 * D, lny_b + 2 * D, yp, 1);
        }
    }
}